// Round 8
// baseline (151.678 us; speedup 1.0000x reference)
//
#include <hip/hip_runtime.h>
#include <hip/hip_bf16.h>
#include <stdint.h>
#include <stddef.h>

// MDCT as folded GEMM, two-kernel structure + XCD-swizzled gemm grid.
//   out[512, 32784] = D[512,512] . V[512, 32784]
//   V[c][j] = j<256:  x[g+j] - x[g+511-j]
//             j>=256: x[g+j+256] + x[g+1279-j],   g = o*512 - 512 (per batch)
// r7: FETCH 66->19.6 MB (XCD swizzle + V L2-resident) but gemm dur unchanged
// -> gemm is DMA-latency-bound: single-buffer K-loop drains vmcnt(0) with
// zero overlap every iter. r8: BK=32 LDS double-buffer (32 KB total, occ 4),
// ONE barrier/iter, DMA for kt+1 issued a full compute phase before its use.
// Swizzle fix vs r6: position = chunk ^ ((row>>1)&3) -> bank group =
// 4*(row&1)+pos covers all 8 groups over 16 consecutive rows (2-way = free).
// Precision: single fp16 product; absmax 0.03125 vs threshold 0.1069.

constexpr int N_ = 512;
constexpr int T_ = 2048;
constexpr int B_ = 16;
constexpr int LEN = N_ * T_;              // 2^20 per batch
constexpr int FRAMES = T_ + 1;            // 2049
constexpr int COLS = B_ * FRAMES;         // 32784
constexpr int NT_TILES = 257;
constexpr int COLS_PAD = NT_TILES * 128;  // 32896
constexpr int KF = 512;
constexpr int BK = 32;
constexpr int KI = KF / BK;               // 16 k-iterations

typedef __attribute__((ext_vector_type(8))) _Float16 f16x8;
typedef __attribute__((ext_vector_type(4))) _Float16 f16x4;
typedef __attribute__((ext_vector_type(4))) float f32x4;

#define GLD16(gptr, lptr)                                                     \
  __builtin_amdgcn_global_load_lds(                                           \
      (const __attribute__((address_space(1))) unsigned int*)(gptr),          \
      (__attribute__((address_space(3))) unsigned int*)(lptr), 16, 0, 0)

// ---------------- Kernel 1: gather filter -> fp16 D -------------------------
__global__ void prep_filter(const float* __restrict__ f,
                            _Float16* __restrict__ D) {
  int idx = (blockIdx.x * 256 + threadIdx.x) * 4;
  int k = idx >> 9;
  int j = idx & 511;
  int t = (j < 256) ? j : (j + 256);
  const float4 v = *(const float4*)&f[k * 1024 + t];
  f16x4 h = {(_Float16)v.x, (_Float16)v.y, (_Float16)v.z, (_Float16)v.w};
  *(f16x4*)&D[k * KF + j] = h;
}

// ---------------- Kernel 2: fold x -> V fp16, one wave per column -----------
// Lane l owns V[c][j0..j0+7]: l<32 -> j0=8l (minus half), l>=32 -> j0=256+8(l-32).
// fwd/rev streams contiguous per half-wave; one f16x8 (16B) store per lane.
__global__ void fold_x(const float* __restrict__ x, _Float16* __restrict__ V) {
  const int c = blockIdx.x * 4 + (threadIdx.x >> 6);  // 4 columns per block
  const int l = threadIdx.x & 63;
  const bool mi = (l < 32);
  const int j0 = mi ? (l * 8) : (256 + (l - 32) * 8);
  const float sgn = mi ? -1.0f : 1.0f;
  float4 a0 = {0.f, 0.f, 0.f, 0.f}, a1 = {0.f, 0.f, 0.f, 0.f};
  float4 r0 = {0.f, 0.f, 0.f, 0.f}, r1 = {0.f, 0.f, 0.f, 0.f};
  if (c < COLS) {
    int b = (int)((unsigned)c / (unsigned)FRAMES);
    int o = c - b * FRAMES;
    const int lo = b * LEN;
    const int g = lo + o * N_ - N_;
    const int fb = g + (mi ? j0 : (j0 + 256));
    const int rb = g + (mi ? (504 - j0) : (1272 - j0));
    if ((unsigned)(fb - lo) <= (unsigned)(LEN - 8)) {
      a0 = *(const float4*)(x + fb);
      a1 = *(const float4*)(x + fb + 4);
    }
    if ((unsigned)(rb - lo) <= (unsigned)(LEN - 8)) {
      r0 = *(const float4*)(x + rb);
      r1 = *(const float4*)(x + rb + 4);
    }
  }
  f16x8 h;
  h[0] = (_Float16)__builtin_fmaf(sgn, r1.w, a0.x);
  h[1] = (_Float16)__builtin_fmaf(sgn, r1.z, a0.y);
  h[2] = (_Float16)__builtin_fmaf(sgn, r1.y, a0.z);
  h[3] = (_Float16)__builtin_fmaf(sgn, r1.x, a0.w);
  h[4] = (_Float16)__builtin_fmaf(sgn, r0.w, a1.x);
  h[5] = (_Float16)__builtin_fmaf(sgn, r0.z, a1.y);
  h[6] = (_Float16)__builtin_fmaf(sgn, r0.y, a1.z);
  h[7] = (_Float16)__builtin_fmaf(sgn, r0.x, a1.w);
  if (c < COLS_PAD) *(f16x8*)&V[(size_t)c * KF + j0] = h;
}

// ---------------- Kernel 3: C = D . V, fp16 MFMA, dbuf BK=32 ----------------
// 128x128 tile, 4 waves (2x2 of 64x64), mfma_f32_16x16x32_f16, 16 MFMA/iter.
// LDS per tile: 128 rows x 4 chunks (16B). slot(row,chunk)=row*4+(chunk^((row>>1)&3)).
// Grid: 1056; id -> xcd=id&7, s=id>>3, m=s&3, nt=(s>>2)*8+xcd; tail exits.
__global__ __launch_bounds__(256, 4) void gemm_fold(
    const _Float16* __restrict__ D, const _Float16* __restrict__ V,
    float* __restrict__ out) {
  __shared__ __align__(16) _Float16 As[2][128 * BK];
  __shared__ __align__(16) _Float16 Bs[2][128 * BK];

  const int id = blockIdx.x;
  const int xcd = id & 7;
  const int sb = id >> 3;
  const int nt = (sb >> 2) * 8 + xcd;
  if (nt >= NT_TILES) return;
  const int m0 = (sb & 3) * 128;
  const int n0 = nt * 128;

  const int tid = threadIdx.x;
  const int wid = tid >> 6;
  const int lane = tid & 63;
  const int quad = lane >> 4;
  const int l16 = lane & 15;
  const int mw = (wid >> 1) * 64;
  const int nw = (wid & 1) * 64;

  const _Float16* Dm = D + (size_t)m0 * KF;
  const _Float16* Vn = V + (size_t)n0 * KF;

  f32x4 acc[4][4];
#pragma unroll
  for (int i = 0; i < 4; ++i)
#pragma unroll
    for (int j = 0; j < 4; ++j) acc[i][j] = (f32x4){0.f, 0.f, 0.f, 0.f};

  // Stage one BK=32 tile pair into buffer `buf`. 512 slots of 16B per matrix;
  // GLD16 dest = uniform base + lane*16 -> slot id S = u*256 + tid; the lane
  // fetches global chunk (S&3) ^ ((row>>1)&3) so fragment reads are swizzled.
  auto stage = [&](int kb, int buf) {
#pragma unroll
    for (int u = 0; u < 2; ++u) {
      const int S = u * 256 + tid;
      const int r = S >> 2;                       // tile row 0..127
      const int c = (S & 3) ^ ((r >> 1) & 3);     // swizzled global chunk
      const int goff = kb + c * 8;                // halves
      GLD16(Dm + (size_t)r * KF + goff, &As[buf][S * 8]);
      GLD16(Vn + (size_t)r * KF + goff, &Bs[buf][S * 8]);
    }
  };

  stage(0, 0);  // prologue: tile 0 in flight

  for (int kt = 0; kt < KI; ++kt) {
    const int cur = kt & 1;
    const int nxt = cur ^ 1;
    // Barrier: (a) per-wave vmcnt(0) drain -> tile kt's DMA complete;
    // (b) all waves done reading buf[nxt] (their ds_reads drained by lgkmcnt).
    __syncthreads();
    if (kt + 1 < KI) stage((kt + 1) * BK, nxt);  // lands during compute below

    f16x8 af[4], bf[4];
#pragma unroll
    for (int i = 0; i < 4; ++i) {
      const int ra = mw + i * 16 + l16;
      const int rb = nw + i * 16 + l16;
      af[i] = *(const f16x8*)&As[cur][(ra * 4 + (quad ^ ((ra >> 1) & 3))) * 8];
      bf[i] = *(const f16x8*)&Bs[cur][(rb * 4 + (quad ^ ((rb >> 1) & 3))) * 8];
    }
#pragma unroll
    for (int i = 0; i < 4; ++i)
#pragma unroll
      for (int j = 0; j < 4; ++j)
        acc[i][j] = __builtin_amdgcn_mfma_f32_16x16x32_f16(af[i], bf[j], acc[i][j], 0, 0, 0);
  }

  // Epilogue (verified r1-r7): C/D layout col = lane&15, row = quad*4 + reg.
#pragma unroll
  for (int i = 0; i < 4; ++i) {
#pragma unroll
    for (int j = 0; j < 4; ++j) {
      int col = n0 + nw + j * 16 + l16;
      if (col < COLS) {
        int b = col / FRAMES;
        int o = col - b * FRAMES;
        int rowb = m0 + mw + i * 16 + quad * 4;
        float* op = out + (size_t)b * N_ * FRAMES + (size_t)rowb * FRAMES + o;
#pragma unroll
        for (int r = 0; r < 4; ++r) op[(size_t)r * FRAMES] = acc[i][j][r];
      }
    }
  }
}

// ---------------- Fallback: direct fp32 conv (if ws too small) --------------
__global__ void naive_conv(const float* __restrict__ x, const float* __restrict__ f,
                           float* __restrict__ out) {
  int col = blockIdx.x;
  int k = threadIdx.x;
  __shared__ float win[1024];
  int b = col / FRAMES;
  int o = col - b * FRAMES;
  const float* xb = x + (size_t)b * LEN;
  int g = o * N_ - N_;
  for (int t = threadIdx.x; t < 1024; t += 512) {
    int i = g + t;
    win[t] = (i >= 0 && i < LEN) ? xb[i] : 0.0f;
  }
  __syncthreads();
  float s = 0.0f;
  const float* fk = f + (size_t)k * 1024;
  for (int t = 0; t < 1024; ++t) s += win[t] * fk[t];
  out[(size_t)b * N_ * FRAMES + (size_t)k * FRAMES + o] = s;
}

extern "C" void kernel_launch(void* const* d_in, const int* in_sizes, int n_in,
                              void* d_out, int out_size, void* d_ws, size_t ws_size,
                              hipStream_t stream) {
  const float* x = (const float*)d_in[0];
  const float* f = (const float*)d_in[1];
  float* out = (float*)d_out;

  const size_t elems_D = (size_t)512 * 512;
  const size_t elems_V = (size_t)COLS_PAD * KF;
  const size_t need = (elems_D + elems_V) * sizeof(_Float16);

  if (ws_size < need) {
    naive_conv<<<COLS, 512, 0, stream>>>(x, f, out);
    return;
  }

  _Float16* D = (_Float16*)d_ws;
  _Float16* V = D + elems_D;

  prep_filter<<<256, 256, 0, stream>>>(f, D);
  fold_x<<<COLS_PAD / 4, 256, 0, stream>>>(x, V);
  // Grid 1056 = 132*8: covers nt=0..256, m=0..3 (max id 1048); tail exits.
  gemm_fold<<<1056, 256, 0, stream>>>(D, V, out);
}